// Round 21
// baseline (112.203 us; speedup 1.0000x reference)
//
#include <hip/hip_runtime.h>

#define NN 50000
#define NE 320000
#define FF 256
#define FILL_B 1250         // ceil(NE/256)
#define XCVT_B 12500        // NN*64/256
#define BPREP_B 128
#define PSTR 64             // padded adjacency stride (max supported in-degree)

typedef short short8 __attribute__((ext_vector_type(8)));
typedef float f32x2 __attribute__((ext_vector_type(2)));
typedef float f32x16 __attribute__((ext_vector_type(16)));
typedef unsigned short us4 __attribute__((ext_vector_type(4)));
typedef unsigned short us8 __attribute__((ext_vector_type(8)));

static __device__ __forceinline__ unsigned short f2bf(float f) {
    union { float f; unsigned u; } v; v.f = f;
    unsigned r = v.u + 0x7FFFu + ((v.u >> 16) & 1u);   // RNE
    return (unsigned short)(r >> 16);
}
static __device__ __forceinline__ float bf2f(unsigned short h) {
    return __uint_as_float((unsigned)h << 16);
}

// ---- fused pre-kernel: {padded-CSR fill | x->bf16+fp8 | B prep (32x32 frags)} -------
// Ab row byte layout: logical byte b stored at b ^ ((row&7)<<4).
// Bp fragment-linear for mfma_32x32x16: frag fb = kc*32 + m*16 + cb  (cb=col/32),
// lane l holds col cb*32+(l&31), k = kc*32 + m*16 + (l>>5)*8 + e.
__global__ __launch_bounds__(256)
void k_pre(const int* __restrict__ ei, int* __restrict__ cnt, int* __restrict__ padded,
           const float* __restrict__ x, unsigned short* __restrict__ Ab,
           unsigned* __restrict__ Xq,
           const float* __restrict__ wi, const float* __restrict__ wr,
           unsigned short* __restrict__ Bp) {
    const int b = blockIdx.x;
    if (b < FILL_B) {
        int e = b * 256 + threadIdx.x;
        if (e < NE) {
            int src = ei[e];
            int dst = ei[NE + e];
            int slot = atomicAdd(&cnt[dst], 1);
            if (slot < PSTR) padded[(size_t)dst * PSTR + slot] = src;
        }
    } else if (b < FILL_B + XCVT_B) {
        int t = (b - FILL_B) * 256 + threadIdx.x;
        if (t < NN * 64) {
            int n = t >> 6, q = t & 63;
            float4 v = *reinterpret_cast<const float4*>(&x[(size_t)n * FF + q * 4]);
            us4 o = {f2bf(v.x), f2bf(v.y), f2bf(v.z), f2bf(v.w)};
            char* rowp = (char*)(Ab + (size_t)n * 512);
            *reinterpret_cast<us4*>(rowp + ((512 + q * 8) ^ ((n & 7) << 4))) = o;
            unsigned u = 0;
            u = __builtin_amdgcn_cvt_pk_fp8_f32(v.x, v.y, u, 0);
            u = __builtin_amdgcn_cvt_pk_fp8_f32(v.z, v.w, u, 1);
            Xq[(size_t)n * 64 + q] = u;
        }
    } else {
        int t = (b - FILL_B - XCVT_B) * 256 + threadIdx.x;   // 0..32767
        int l = t & 63;
        int fb = t >> 6;          // 0..511
        int cb = fb & 15;         // col block (32 cols)
        int km = fb >> 4;         // 0..31
        int kc = km >> 1;
        int m  = km & 1;
        int col = cb * 32 + (l & 31);
        int kpart = col >> 8;
        int g = col & 255;
        int K0 = kc * 32 + m * 16 + (l >> 5) * 8;
        unsigned short* dst = Bp + (size_t)fb * 512 + (size_t)l * 8;
        #pragma unroll
        for (int e = 0; e < 8; ++e) {
            int K = K0 + e;
            const float* srcp = (K < 256) ? wi : wr;
            float v = srcp[(size_t)kpart * 65536 + (size_t)(K & 255) * 256 + g];
            dst[e] = f2bf(v);
        }
    }
}

// ---- aggregation v4 (R19 proven): 2 nodes/wave, fp8 gather, bf16 y output -----------
__global__ __launch_bounds__(256)
void k_agg(const int* __restrict__ cnt, const int* __restrict__ padded,
           const unsigned* __restrict__ Xq, unsigned short* __restrict__ Ab) {
    int wid = (blockIdx.x * blockDim.x + threadIdx.x) >> 6;
    if (wid >= NN / 2) return;
    int l = threadIdx.x & 63;
    int n = wid * 2 + (l >> 5);
    int d = cnt[n];
    float di = d > 0 ? rsqrtf((float)d) : 0.f;
    if (d > PSTR) d = PSTR;
    const int* pp = padded + (size_t)n * PSTR;
    const int lw = (l & 31) * 2;
    float acc[8];
    #pragma unroll
    for (int j = 0; j < 8; ++j) acc[j] = 0.f;

    #define DECODE_FMA(vv, ww)                                                    \
        {                                                                         \
            f32x2 f01 = __builtin_amdgcn_cvt_pk_f32_fp8((vv).x, 0);               \
            f32x2 f23 = __builtin_amdgcn_cvt_pk_f32_fp8((vv).x, 1);               \
            f32x2 f45 = __builtin_amdgcn_cvt_pk_f32_fp8((vv).y, 0);               \
            f32x2 f67 = __builtin_amdgcn_cvt_pk_f32_fp8((vv).y, 1);               \
            acc[0] = fmaf(ww, f01[0], acc[0]);                                    \
            acc[1] = fmaf(ww, f01[1], acc[1]);                                    \
            acc[2] = fmaf(ww, f23[0], acc[2]);                                    \
            acc[3] = fmaf(ww, f23[1], acc[3]);                                    \
            acc[4] = fmaf(ww, f45[0], acc[4]);                                    \
            acc[5] = fmaf(ww, f45[1], acc[5]);                                    \
            acc[6] = fmaf(ww, f67[0], acc[6]);                                    \
            acc[7] = fmaf(ww, f67[1], acc[7]);                                    \
        }

    int e = 0;
    for (; e + 4 <= d; e += 4) {
        int s0 = pp[e + 0];
        int s1 = pp[e + 1];
        int s2 = pp[e + 2];
        int s3 = pp[e + 3];
        uint2 v0 = *reinterpret_cast<const uint2*>(Xq + (size_t)s0 * 64 + lw);
        uint2 v1 = *reinterpret_cast<const uint2*>(Xq + (size_t)s1 * 64 + lw);
        uint2 v2 = *reinterpret_cast<const uint2*>(Xq + (size_t)s2 * 64 + lw);
        uint2 v3 = *reinterpret_cast<const uint2*>(Xq + (size_t)s3 * 64 + lw);
        int c0 = cnt[s0], c1 = cnt[s1], c2 = cnt[s2], c3 = cnt[s3];
        float w0 = di * (c0 > 0 ? rsqrtf((float)c0) : 0.f);
        float w1 = di * (c1 > 0 ? rsqrtf((float)c1) : 0.f);
        float w2 = di * (c2 > 0 ? rsqrtf((float)c2) : 0.f);
        float w3 = di * (c3 > 0 ? rsqrtf((float)c3) : 0.f);
        DECODE_FMA(v0, w0)
        DECODE_FMA(v1, w1)
        DECODE_FMA(v2, w2)
        DECODE_FMA(v3, w3)
    }
    for (; e < d; ++e) {
        int s0 = pp[e];
        uint2 v0 = *reinterpret_cast<const uint2*>(Xq + (size_t)s0 * 64 + lw);
        int c0 = cnt[s0];
        float w0 = di * (c0 > 0 ? rsqrtf((float)c0) : 0.f);
        DECODE_FMA(v0, w0)
    }
    #undef DECODE_FMA

    us8 o;
    #pragma unroll
    for (int j = 0; j < 8; ++j) o[j] = f2bf(acc[j]);
    const int lq = (l & 31) * 16;
    *reinterpret_cast<us8*>((char*)Ab + (size_t)n * 1024 + (lq ^ ((n & 7) << 4))) = o;
}

// ---- MFMA GEMM + epilogue: 32x32x16 MFMA, BM=64, split-K staging, counted vmcnt -----
// LDS: Y panel [64][512B] at 0, X panel [64][512B] at 32768 (swizzled rows).
// Wave w: col blocks cb=w (k0, cols w*32..) and cb=8+w (k1). acc[2 rowfrag][2 cb] f32x16.
// A frag (assumed, analog of verified 16x16x32): row=l&31, k=(l>>5)*8+e.
// Per kc: 4 ds_read_b128 (half of the 16x16 path) + 4 B loads + 8 MFMA_32x32.
#define LOADB(dst, kc_)                                                           \
    {                                                                             \
        dst[0] = *reinterpret_cast<const short8*>(bpb + ((kc_) * 32 + w) * 1024);           \
        dst[1] = *reinterpret_cast<const short8*>(bpb + ((kc_) * 32 + 8 + w) * 1024);       \
        dst[2] = *reinterpret_cast<const short8*>(bpb + ((kc_) * 32 + 16 + w) * 1024);      \
        dst[3] = *reinterpret_cast<const short8*>(bpb + ((kc_) * 32 + 24 + w) * 1024);      \
    }
#define LOADA(d0, d1, bp_, h_)                                                    \
    {                                                                             \
        d0[0] = *reinterpret_cast<const short8*>((bp_) + (h_) * 128 + mo0);               \
        d0[1] = *reinterpret_cast<const short8*>((bp_) + 16384 + (h_) * 128 + mo0);       \
        d1[0] = *reinterpret_cast<const short8*>((bp_) + (h_) * 128 + mo1);               \
        d1[1] = *reinterpret_cast<const short8*>((bp_) + 16384 + (h_) * 128 + mo1);       \
    }
#define MFMA_KC(am0, am1, bset)                                                   \
    {                                                                             \
        acc[0][0] = __builtin_amdgcn_mfma_f32_32x32x16_bf16(am0[0], bset[0], acc[0][0], 0, 0, 0); \
        acc[1][0] = __builtin_amdgcn_mfma_f32_32x32x16_bf16(am0[1], bset[0], acc[1][0], 0, 0, 0); \
        acc[0][1] = __builtin_amdgcn_mfma_f32_32x32x16_bf16(am0[0], bset[1], acc[0][1], 0, 0, 0); \
        acc[1][1] = __builtin_amdgcn_mfma_f32_32x32x16_bf16(am0[1], bset[1], acc[1][1], 0, 0, 0); \
        acc[0][0] = __builtin_amdgcn_mfma_f32_32x32x16_bf16(am1[0], bset[2], acc[0][0], 0, 0, 0); \
        acc[1][0] = __builtin_amdgcn_mfma_f32_32x32x16_bf16(am1[1], bset[2], acc[1][0], 0, 0, 0); \
        acc[0][1] = __builtin_amdgcn_mfma_f32_32x32x16_bf16(am1[0], bset[3], acc[0][1], 0, 0, 0); \
        acc[1][1] = __builtin_amdgcn_mfma_f32_32x32x16_bf16(am1[1], bset[3], acc[1][1], 0, 0, 0); \
    }

__global__ __launch_bounds__(512, 4)
void k_mm(const unsigned short* __restrict__ Ab, const unsigned short* __restrict__ Bp,
          const float* __restrict__ bias, float* __restrict__ out) {
    __shared__ char smem[65536];   // [Y 64x512B | X 64x512B], swizzled rows

    const int l = threadIdx.x & 63;
    const int w = threadIdx.x >> 6;      // 0..7
    const int row0 = blockIdx.x * 64;
    const char* base = (const char*)Ab;

    // ---- stage Y halves: wave w rows w*8..w*8+7, 4 issues of 2 rows (1KB each)
    #pragma unroll
    for (int j = 0; j < 4; ++j) {
        int rl = w * 8 + 2 * j;
        int r = row0 + rl + (l >> 5);
        if (r >= NN) r = NN - 1;
        const char* gp = base + (size_t)r * 1024 + (l & 31) * 16;
        __builtin_amdgcn_global_load_lds(
            (const __attribute__((address_space(1))) void*)gp,
            (__attribute__((address_space(3))) void*)(smem + rl * 512),
            16, 0, 0);
    }
    // ---- stage X halves (global byte +512, LDS panel +32768)
    #pragma unroll
    for (int j = 0; j < 4; ++j) {
        int rl = w * 8 + 2 * j;
        int r = row0 + rl + (l >> 5);
        if (r >= NN) r = NN - 1;
        const char* gp = base + (size_t)r * 1024 + 512 + (l & 31) * 16;
        __builtin_amdgcn_global_load_lds(
            (const __attribute__((address_space(1))) void*)gp,
            (__attribute__((address_space(3))) void*)(smem + 32768 + rl * 512),
            16, 0, 0);
    }

    f32x16 acc[2][2] = {};               // [row frag 0/1][cb: 0=k0(w), 1=k1(8+w)]

    // A addressing with row-swizzle folded in (rows rb*32 + (l&31)):
    // logical byte in row = kc*64 + m*32 + (l>>5)*16; stored byte = logical ^ ((row&7)<<4)
    // row&7 = l&7 = p -> bit4 ^= p0, bit5 ^= p1, bit6 ^= p2.
    const int q2 = l >> 5;
    const int p0 = l & 1, p1 = (l >> 1) & 1, p2 = (l >> 2) & 1;
    const int aoff = (l & 31) * 512 + ((q2 ^ p0) << 4);
    const int mo0 = p1 << 5;             // m=0 stored bit5
    const int mo1 = (1 ^ p1) << 5;       // m=1
    const int ke = p2 << 6;              // even kc stored bit6
    const int ko = (1 ^ p2) << 6;        // odd kc
    const char* yE = smem + aoff + ke;
    const char* yO = smem + aoff + ko;
    const char* xE = smem + 32768 + aoff + ke;
    const char* xO = smem + 32768 + aoff + ko;
    const char* bpb = (const char*)(Bp + (size_t)l * 8);

    short8 a0[2], a1[2], b0[4], b1[4];
    LOADB(b0, 0)                       // outstanding: 4Y + 4X + 4B = 12

    asm volatile("s_waitcnt vmcnt(8)" ::: "memory");   // Y staged (X + b0 in flight)
    __builtin_amdgcn_s_barrier();
    __builtin_amdgcn_sched_barrier(0);

    #pragma unroll 1
    for (int kc2 = 0; kc2 < 4; ++kc2) {          // kc 0..7 (Y half)
        LOADA(a0, a1, yE, kc2)
        LOADB(b1, 2 * kc2 + 1)
        MFMA_KC(a0, a1, b0)
        LOADA(a0, a1, yO, kc2)
        LOADB(b0, 2 * kc2 + 2)
        MFMA_KC(a0, a1, b1)
    }
    asm volatile("s_waitcnt vmcnt(4)" ::: "memory");   // X staged
    __builtin_amdgcn_s_barrier();
    __builtin_amdgcn_sched_barrier(0);

    #pragma unroll 1
    for (int kc2 = 0; kc2 < 3; ++kc2) {          // kc 8..13 (X half)
        LOADA(a0, a1, xE, kc2)
        LOADB(b1, 9 + 2 * kc2)
        MFMA_KC(a0, a1, b0)
        LOADA(a0, a1, xO, kc2)
        LOADB(b0, 10 + 2 * kc2)
        MFMA_KC(a0, a1, b1)
    }
    {                                            // kc 14,15 tail
        LOADA(a0, a1, xE, 3)
        LOADB(b1, 15)
        MFMA_KC(a0, a1, b0)
        LOADA(a0, a1, xO, 3)
        MFMA_KC(a0, a1, b1)
    }

    // ---- epilogue: C/D layout (verified m74/m101): col=l&31, row=(reg&3)+8*(reg>>2)+4*q2
    const int gg = w * 32 + (l & 31);
    const float bv0 = bias[gg], bv1 = bias[256 + gg];
    #pragma unroll
    for (int rb = 0; rb < 2; ++rb) {
        #pragma unroll
        for (int reg = 0; reg < 16; ++reg) {
            int rl = rb * 32 + (reg & 3) + 8 * (reg >> 2) + 4 * q2;
            int r = row0 + rl;
            if (r >= NN) continue;
            int sw = (rl & 7) << 4;
            unsigned short xb =
                *reinterpret_cast<const unsigned short*>(&smem[32768 + rl * 512 + ((gg * 2) ^ sw)]);
            float xv = bf2f(xb);
            float c0 = acc[rb][0][reg] + bv0;
            float c1 = acc[rb][1][reg] + bv1;
            float arma = 0.5f * (fmaxf(c0, 0.f) + fmaxf(c1, 0.f));
            out[(size_t)r * FF + gg] = xv + fmaxf(arma, 0.f);
        }
    }
}

extern "C" void kernel_launch(void* const* d_in, const int* in_sizes, int n_in,
                              void* d_out, int out_size, void* d_ws, size_t ws_size,
                              hipStream_t stream) {
    const float* x    = (const float*)d_in[0];
    const int*   ei   = (const int*)d_in[1];
    const float* wi   = (const float*)d_in[2];
    const float* wr   = (const float*)d_in[3];
    const float* bias = (const float*)d_in[4];
    float* out = (float*)d_out;

    // workspace (~26.3 MB)
    int* cnt    = (int*)d_ws;                                // NN
    int* padded = cnt + NN;                                  // NN * PSTR
    unsigned short* Bp = (unsigned short*)(padded + (size_t)NN * PSTR);  // 512*512 bf16
    unsigned* Xq = (unsigned*)(Bp + 512 * 512);              // NN * 64 uints (fp8 x)
    unsigned short* Ab = (unsigned short*)d_out;             // NN x 512 bf16

    hipMemsetAsync(cnt, 0, NN * sizeof(int), stream);

    k_pre<<<FILL_B + XCVT_B + BPREP_B, 256, 0, stream>>>(ei, cnt, padded, x, Ab, Xq, wi, wr, Bp);
    k_agg<<<(NN / 2 * 64 + 255) / 256, 256, 0, stream>>>(cnt, padded, Xq, Ab);
    k_mm <<<(NN + 63) / 64, 512, 0, stream>>>(Ab, Bp, bias, out);
}

// Round 22
// 104.729 us; speedup vs baseline: 1.0714x; 1.0714x over previous
//
#include <hip/hip_runtime.h>

#define NN 50000
#define NE 320000
#define FF 256
#define FILL_B 1250         // ceil(NE/256)
#define XCVT_B 12500        // NN*64/256
#define BPREP_B 128
#define PSTR 64             // padded adjacency stride (max supported in-degree)

typedef short short8 __attribute__((ext_vector_type(8)));
typedef float f32x4 __attribute__((ext_vector_type(4)));
typedef float f32x2 __attribute__((ext_vector_type(2)));
typedef unsigned short us4 __attribute__((ext_vector_type(4)));
typedef unsigned short us8 __attribute__((ext_vector_type(8)));

static __device__ __forceinline__ unsigned short f2bf(float f) {
    union { float f; unsigned u; } v; v.f = f;
    unsigned r = v.u + 0x7FFFu + ((v.u >> 16) & 1u);   // RNE
    return (unsigned short)(r >> 16);
}
static __device__ __forceinline__ float bf2f(unsigned short h) {
    return __uint_as_float((unsigned)h << 16);
}

// ---- fused pre-kernel: {padded-CSR fill | x->bf16+fp8 | B prep} ---------------------
// Ab row byte layout: logical byte b stored at b ^ ((row&7)<<4).
__global__ __launch_bounds__(256)
void k_pre(const int* __restrict__ ei, int* __restrict__ cnt, int* __restrict__ padded,
           const float* __restrict__ x, unsigned short* __restrict__ Ab,
           unsigned* __restrict__ Xq,
           const float* __restrict__ wi, const float* __restrict__ wr,
           unsigned short* __restrict__ Bp) {
    const int b = blockIdx.x;
    if (b < FILL_B) {
        int e = b * 256 + threadIdx.x;
        if (e < NE) {
            int src = ei[e];
            int dst = ei[NE + e];
            int slot = atomicAdd(&cnt[dst], 1);
            if (slot < PSTR) padded[(size_t)dst * PSTR + slot] = src;
        }
    } else if (b < FILL_B + XCVT_B) {
        int t = (b - FILL_B) * 256 + threadIdx.x;
        if (t < NN * 64) {
            int n = t >> 6, q = t & 63;
            float4 v = *reinterpret_cast<const float4*>(&x[(size_t)n * FF + q * 4]);
            us4 o = {f2bf(v.x), f2bf(v.y), f2bf(v.z), f2bf(v.w)};
            char* rowp = (char*)(Ab + (size_t)n * 512);
            *reinterpret_cast<us4*>(rowp + ((512 + q * 8) ^ ((n & 7) << 4))) = o;
            unsigned u = 0;
            u = __builtin_amdgcn_cvt_pk_fp8_f32(v.x, v.y, u, 0);
            u = __builtin_amdgcn_cvt_pk_fp8_f32(v.z, v.w, u, 1);
            Xq[(size_t)n * 64 + q] = u;
        }
    } else {
        int t = (b - FILL_B - XCVT_B) * 256 + threadIdx.x;   // 0..32767
        int l = t & 63;
        int fb = t >> 6;          // 0..511
        int kc = fb >> 5;
        int cf = fb & 31;
        int col = cf * 16 + (l & 15);
        int kpart = col >> 8;
        int g = col & 255;
        int K0 = kc * 32 + (l >> 4) * 8;
        unsigned short* dst = Bp + (size_t)fb * 512 + (size_t)l * 8;
        #pragma unroll
        for (int e = 0; e < 8; ++e) {
            int K = K0 + e;
            const float* srcp = (K < 256) ? wi : wr;
            float v = srcp[(size_t)kpart * 65536 + (size_t)(K & 255) * 256 + g];
            dst[e] = f2bf(v);
        }
    }
}

// ---- aggregation v4 (R19 proven): 2 nodes/wave, fp8 gather, bf16 y output -----------
__global__ __launch_bounds__(256)
void k_agg(const int* __restrict__ cnt, const int* __restrict__ padded,
           const unsigned* __restrict__ Xq, unsigned short* __restrict__ Ab) {
    int wid = (blockIdx.x * blockDim.x + threadIdx.x) >> 6;
    if (wid >= NN / 2) return;
    int l = threadIdx.x & 63;
    int n = wid * 2 + (l >> 5);
    int d = cnt[n];
    float di = d > 0 ? rsqrtf((float)d) : 0.f;
    if (d > PSTR) d = PSTR;
    const int* pp = padded + (size_t)n * PSTR;
    const int lw = (l & 31) * 2;
    float acc[8];
    #pragma unroll
    for (int j = 0; j < 8; ++j) acc[j] = 0.f;

    #define DECODE_FMA(vv, ww)                                                    \
        {                                                                         \
            f32x2 f01 = __builtin_amdgcn_cvt_pk_f32_fp8((vv).x, 0);               \
            f32x2 f23 = __builtin_amdgcn_cvt_pk_f32_fp8((vv).x, 1);               \
            f32x2 f45 = __builtin_amdgcn_cvt_pk_f32_fp8((vv).y, 0);               \
            f32x2 f67 = __builtin_amdgcn_cvt_pk_f32_fp8((vv).y, 1);               \
            acc[0] = fmaf(ww, f01[0], acc[0]);                                    \
            acc[1] = fmaf(ww, f01[1], acc[1]);                                    \
            acc[2] = fmaf(ww, f23[0], acc[2]);                                    \
            acc[3] = fmaf(ww, f23[1], acc[3]);                                    \
            acc[4] = fmaf(ww, f45[0], acc[4]);                                    \
            acc[5] = fmaf(ww, f45[1], acc[5]);                                    \
            acc[6] = fmaf(ww, f67[0], acc[6]);                                    \
            acc[7] = fmaf(ww, f67[1], acc[7]);                                    \
        }

    int e = 0;
    for (; e + 4 <= d; e += 4) {
        int s0 = pp[e + 0];
        int s1 = pp[e + 1];
        int s2 = pp[e + 2];
        int s3 = pp[e + 3];
        uint2 v0 = *reinterpret_cast<const uint2*>(Xq + (size_t)s0 * 64 + lw);
        uint2 v1 = *reinterpret_cast<const uint2*>(Xq + (size_t)s1 * 64 + lw);
        uint2 v2 = *reinterpret_cast<const uint2*>(Xq + (size_t)s2 * 64 + lw);
        uint2 v3 = *reinterpret_cast<const uint2*>(Xq + (size_t)s3 * 64 + lw);
        int c0 = cnt[s0], c1 = cnt[s1], c2 = cnt[s2], c3 = cnt[s3];
        float w0 = di * (c0 > 0 ? rsqrtf((float)c0) : 0.f);
        float w1 = di * (c1 > 0 ? rsqrtf((float)c1) : 0.f);
        float w2 = di * (c2 > 0 ? rsqrtf((float)c2) : 0.f);
        float w3 = di * (c3 > 0 ? rsqrtf((float)c3) : 0.f);
        DECODE_FMA(v0, w0)
        DECODE_FMA(v1, w1)
        DECODE_FMA(v2, w2)
        DECODE_FMA(v3, w3)
    }
    for (; e < d; ++e) {
        int s0 = pp[e];
        uint2 v0 = *reinterpret_cast<const uint2*>(Xq + (size_t)s0 * 64 + lw);
        int c0 = cnt[s0];
        float w0 = di * (c0 > 0 ? rsqrtf((float)c0) : 0.f);
        DECODE_FMA(v0, w0)
    }
    #undef DECODE_FMA

    us8 o;
    #pragma unroll
    for (int j = 0; j < 8; ++j) o[j] = f2bf(acc[j]);
    const int lq = (l & 31) * 16;
    *reinterpret_cast<us8*>((char*)Ab + (size_t)n * 1024 + (lq ^ ((n & 7) << 4))) = o;
}

// ---- MFMA GEMM + epilogue (R18/R19 proven: split-K staging, counted vmcnt) ----------
#define LOADB(dst, kc_)                                                           \
    {                                                                             \
        dst[0] = *reinterpret_cast<const short8*>(bpb + (kc_) * 32768 + (2 * w + 0) * 1024);        \
        dst[1] = *reinterpret_cast<const short8*>(bpb + (kc_) * 32768 + (2 * w + 1) * 1024);        \
        dst[2] = *reinterpret_cast<const short8*>(bpb + (kc_) * 32768 + (16 + 2 * w) * 1024);       \
        dst[3] = *reinterpret_cast<const short8*>(bpb + (kc_) * 32768 + (17 + 2 * w) * 1024);       \
    }
#define LOADAF(dst, ab, h_)                                                       \
    {                                                                             \
        _Pragma("unroll")                                                         \
        for (int rf = 0; rf < 4; ++rf)                                            \
            dst[rf] = *reinterpret_cast<const short8*>((ab) + rf * 8192 + (h_) * 128); \
    }
#define MFMA4(aset, bset)                                                         \
    {                                                                             \
        _Pragma("unroll")                                                         \
        for (int rf = 0; rf < 4; ++rf)                                            \
            _Pragma("unroll")                                                     \
            for (int c = 0; c < 4; ++c)                                           \
                acc[rf][c] = __builtin_amdgcn_mfma_f32_16x16x32_bf16(aset[rf], bset[c], acc[rf][c], 0, 0, 0); \
    }

__global__ __launch_bounds__(512, 4)
void k_mm(const unsigned short* __restrict__ Ab, const unsigned short* __restrict__ Bp,
          const float* __restrict__ bias, float* __restrict__ out) {
    __shared__ char smem[65536];   // [Y 64x512B | X 64x512B], swizzled rows

    const int l = threadIdx.x & 63;
    const int w = threadIdx.x >> 6;
    const int row0 = blockIdx.x * 64;
    const char* base = (const char*)Ab;

    // ---- stage Y halves: wave w rows w*8..w*8+7, 4 issues of 2 rows (1KB each)
    #pragma unroll
    for (int j = 0; j < 4; ++j) {
        int rl = w * 8 + 2 * j;
        int r = row0 + rl + (l >> 5);
        if (r >= NN) r = NN - 1;
        const char* gp = base + (size_t)r * 1024 + (l & 31) * 16;
        __builtin_amdgcn_global_load_lds(
            (const __attribute__((address_space(1))) void*)gp,
            (__attribute__((address_space(3))) void*)(smem + rl * 512),
            16, 0, 0);
    }
    // ---- stage X halves (same rows, global byte +512, LDS panel +32768)
    #pragma unroll
    for (int j = 0; j < 4; ++j) {
        int rl = w * 8 + 2 * j;
        int r = row0 + rl + (l >> 5);
        if (r >= NN) r = NN - 1;
        const char* gp = base + (size_t)r * 1024 + 512 + (l & 31) * 16;
        __builtin_amdgcn_global_load_lds(
            (const __attribute__((address_space(1))) void*)gp,
            (__attribute__((address_space(3))) void*)(smem + 32768 + rl * 512),
            16, 0, 0);
    }

    f32x4 acc[4][4];
    #pragma unroll
    for (int i = 0; i < 4; ++i)
        #pragma unroll
        for (int j = 0; j < 4; ++j) acc[i][j] = (f32x4){0.f, 0.f, 0.f, 0.f};

    const int p = l & 7, q = l >> 4;
    const int aoff = (l & 15) * 512 + ((p >> 2) << 6) + ((q ^ (p & 3)) << 4);
    const char* yE = smem + aoff;
    const char* yO = smem + (aoff ^ 64);
    const char* xE = smem + 32768 + aoff;
    const char* xO = smem + 32768 + (aoff ^ 64);
    const char* bpb = (const char*)(Bp + (size_t)l * 8);

    short8 a[4], b0[4], b1[4];
    LOADB(b0, 0)                       // outstanding: 4Y + 4X + 4B

    asm volatile("s_waitcnt vmcnt(8)" ::: "memory");
    __builtin_amdgcn_s_barrier();
    __builtin_amdgcn_sched_barrier(0);

    #pragma unroll 1
    for (int kc2 = 0; kc2 < 4; ++kc2) {          // kc 0..7 (Y half)
        LOADAF(a, yE, kc2)
        LOADB(b1, 2 * kc2 + 1)
        MFMA4(a, b0)
        LOADAF(a, yO, kc2)
        LOADB(b0, 2 * kc2 + 2)
        MFMA4(a, b1)
    }
    asm volatile("s_waitcnt vmcnt(4)" ::: "memory");
    __builtin_amdgcn_s_barrier();
    __builtin_amdgcn_sched_barrier(0);

    #pragma unroll 1
    for (int kc2 = 0; kc2 < 3; ++kc2) {          // kc 8..13 (X half)
        LOADAF(a, xE, kc2)
        LOADB(b1, 9 + 2 * kc2)
        MFMA4(a, b0)
        LOADAF(a, xO, kc2)
        LOADB(b0, 10 + 2 * kc2)
        MFMA4(a, b1)
    }
    {                                            // kc 14,15 tail
        LOADAF(a, xE, 3)
        LOADB(b1, 15)
        MFMA4(a, b0)
        LOADAF(a, xO, 3)
        MFMA4(a, b1)
    }

    // ---- epilogue: residual x from LDS X panel
    #pragma unroll
    for (int rf = 0; rf < 4; ++rf) {
        const int rl0 = rf * 16 + (l >> 4) * 4;
        #pragma unroll
        for (int j = 0; j < 4; ++j) {
            int rl = rl0 + j;
            int r = row0 + rl;
            if (r >= NN) continue;
            int sw = (rl & 7) << 4;
            #pragma unroll
            for (int c = 0; c < 2; ++c) {
                int gg = w * 32 + c * 16 + (l & 15);
                unsigned short xb =
                    *reinterpret_cast<const unsigned short*>(&smem[32768 + rl * 512 + ((gg * 2) ^ sw)]);
                float xv = bf2f(xb);
                float c0 = acc[rf][c][j] + bias[gg];
                float c1 = acc[rf][c + 2][j] + bias[256 + gg];
                float arma = 0.5f * (fmaxf(c0, 0.f) + fmaxf(c1, 0.f));
                out[(size_t)r * FF + gg] = xv + fmaxf(arma, 0.f);
            }
        }
    }
}

extern "C" void kernel_launch(void* const* d_in, const int* in_sizes, int n_in,
                              void* d_out, int out_size, void* d_ws, size_t ws_size,
                              hipStream_t stream) {
    const float* x    = (const float*)d_in[0];
    const int*   ei   = (const int*)d_in[1];
    const float* wi   = (const float*)d_in[2];
    const float* wr   = (const float*)d_in[3];
    const float* bias = (const float*)d_in[4];
    float* out = (float*)d_out;

    // workspace (~26.3 MB)
    int* cnt    = (int*)d_ws;                                // NN
    int* padded = cnt + NN;                                  // NN * PSTR
    unsigned short* Bp = (unsigned short*)(padded + (size_t)NN * PSTR);  // 512*512 bf16
    unsigned* Xq = (unsigned*)(Bp + 512 * 512);              // NN * 64 uints (fp8 x)
    unsigned short* Ab = (unsigned short*)d_out;             // NN x 512 bf16

    hipMemsetAsync(cnt, 0, NN * sizeof(int), stream);

    k_pre<<<FILL_B + XCVT_B + BPREP_B, 256, 0, stream>>>(ei, cnt, padded, x, Ab, Xq, wi, wr, Bp);
    k_agg<<<(NN / 2 * 64 + 255) / 256, 256, 0, stream>>>(cnt, padded, Xq, Ab);
    k_mm <<<(NN + 63) / 64, 512, 0, stream>>>(Ab, Bp, bias, out);
}